// Round 12
// baseline (144.333 us; speedup 1.0000x reference)
//
#include <hip/hip_runtime.h>
#include <stdint.h>

// CoEncoderDynamicAttention: B=2,S=2048,H=1024,NH=16,NKV=4,HD=64, out=(B,S,1)
// out[b,q] = sum_h (sum_k e_{hqk} * vproj[b,h,k]) / (sum_k e_{hqk})
// vproj = hs @ (wv folded with wo); Q' = hs@wq*(log2e/8); weight = exp2(Q'.K);
// mask folded as MFMA accumulator-init bias (0/-30000) -> exp2 gives exact 0.
// R1 gemm dbuf; R2 attn 2048-block structure + setprio; R3 XCD remap + packed
// f32x2 accumulate; R4 attn K via swizzled global_load_lds; R5 gemm 64-r tiles
// + K-DMA-first; R6a hs_bf eliminated; R7 revert fence-based combine fusion;
// R8 gemm counted-vmcnt; R9 reg-staged bf16 B; R11 revert R10 occupancy loss.
// R12: (a) combine fused into attn FENCE-FREE: relaxed agent-scope (sc1)
//      atomic stores for part + vmcnt(0)+relaxed agent fetch_add counter +
//      last-arriver reduces via agent loads. No buffer_wbl2 anywhere (R6b's
//      2048x threadfence storm avoided by construction). (b) gemm 4 LDS
//      buffers -> ONE barrier/K-iter (DMA target t+2 mod 4 no longer aliases
//      the buffer read at t-1, so the post-compute barrier is redundant).

typedef __bf16 bf16x8 __attribute__((ext_vector_type(8)));
typedef float f32x4 __attribute__((ext_vector_type(4)));
typedef float f32x2 __attribute__((ext_vector_type(2)));

__device__ inline unsigned short f2bf(float f) {
    unsigned int u = __builtin_bit_cast(unsigned int, f);
    u += 0x7fff + ((u >> 16) & 1);   // RNE
    return (unsigned short)(u >> 16);
}
__device__ inline bf16x8 ldfrag(const unsigned short* p) {
    uint4 v = *(const uint4*)p;
    return __builtin_bit_cast(bf16x8, v);
}
__device__ inline void gl2lds16(const void* g, void* l) {
    // 64 lanes x 16B: per-lane global addr, LDS dst = wave-uniform base + lane*16
    __builtin_amdgcn_global_load_lds(
        (const __attribute__((address_space(1))) void*)g,
        (__attribute__((address_space(3))) void*)l, 16, 0, 0);
}

#define SCALE_Q 0.18033688011112042f   // log2(e)/8

// ---------------- prep: wT = [wq^T*s | wk^T | wvo^T | zeros] (1408x1024 bf16);
// zero last-arriver counters (re-poison-safe each graph replay)
__global__ __launch_bounds__(256) void prep_kernel(
    const float* __restrict__ wq, const float* __restrict__ wk,
    const float* __restrict__ wv, const float* __restrict__ wo,
    unsigned short* __restrict__ wT, int* __restrict__ cnt)
{
    int bid = blockIdx.x, tid = threadIdx.x;
    if (bid < 320) {
        __shared__ float tile[64 * 65];
        int t = bid;
        int ntile = t / 16, ctile = t % 16;
        int nb = ntile * 64, cb = ctile * 64;
        int tx = tid & 63, ty = tid >> 6;
        for (int i = 0; i < 16; i++) {
            int cl = i * 4 + ty;
            int n = nb + tx;
            float v = (n < 1024) ? wq[(cb + cl) * 1024 + n] * SCALE_Q
                                 : wk[(cb + cl) * 256 + (n - 1024)];
            tile[cl * 65 + tx] = v;
        }
        __syncthreads();
        for (int i = 0; i < 16; i++) {
            int nl = i * 4 + ty;
            wT[(nb + nl) * 1024 + cb + tx] = f2bf(tile[tx * 65 + nl]);
        }
    } else {
        if (bid == 320 && tid < 64)
            __hip_atomic_store(cnt + tid, 0, __ATOMIC_RELAXED, __HIP_MEMORY_SCOPE_AGENT);
        int u = (bid - 320) * 256 + tid;
        int n2 = u >> 10, c = u & 1023;
        if (n2 < 16) {
            int h = n2, kv = h >> 2;
            const float* wvr = wv + c * 256 + kv * 64;
            const float* wor = wo + h * 64;
            float s = 0.f;
            #pragma unroll 8
            for (int d = 0; d < 64; d++) s += wvr[d] * wor[d];
            wT[(1280 + n2) * 1024 + c] = f2bf(s);
        } else {
            wT[(1280 + n2) * 1024 + c] = 0;
        }
    }
}

// ---------------- gemm (4-buf, ONE barrier/iter, counted vmcnt, reg-staged
// bf16 B, XCD remap, 128n x 64r): D[n][r] = sum_c wT[n][c]*hs[r][c].
// n-tiles: 0..7 Q', 8..9 K, 10 vproj f32.
__global__ __launch_bounds__(256) void gemm_kernel(
    const float* __restrict__ hs, const unsigned short* __restrict__ wT,
    unsigned short* __restrict__ Qp, unsigned short* __restrict__ Kp,
    float* __restrict__ vproj)
{
    __shared__ __align__(16) unsigned short Al[4][128 * 32];  // 32 KB
    __shared__ __align__(16) unsigned short Bl[4][64 * 32];   // 16 KB
    // XCD remap: XCD x gets rt-groups x*8..x*8+7 (88 = 8rt x 11nt).
    int p = blockIdx.x + 11 * blockIdx.y;   // 0..703
    int xcd = p & 7;
    int j = p >> 3;                          // 0..87
    int rt = (xcd << 3) + j / 11;            // 0..63
    int nt = j % 11;
    int tid = threadIdx.x;
    int lane = tid & 63, w = tid >> 6;
    int l15 = lane & 15, quad = lane >> 4;
    int wm = (w >> 1) * 64, wn = (w & 1) * 32;

    f32x4 acc[4][2];
    const f32x4 zero = {0.f, 0.f, 0.f, 0.f};
    for (int i = 0; i < 4; i++) for (int j2 = 0; j2 < 2; j2++) acc[i][j2] = zero;

    int arow = nt * 128, rrow = rt * 64;
    int srowA = w * 32 + (lane >> 2);
    int scolA = (lane & 3) * 8;
    const unsigned short* ga = wT + (size_t)(arow + srowA) * 1024 + scolA;
    int lofsA = (w * 32) * 32;
    int rWl = w * 16 + (lane >> 2);          // 0..63 within tile
    const float* gb = hs + (size_t)(rrow + rWl) * 1024 + (lane & 3) * 8;
    int bwofs = rWl * 32 + (lane & 3) * 8;

    float4 e0a, e0b, e1a, e1b;               // 2 B-reg slots (tile parity)

#define STAGE_A(SB) \
    gl2lds16(ga,             Al[SB] + lofsA); \
    gl2lds16(ga + 16 * 1024, Al[SB] + lofsA + 16 * 32); \
    ga += 32;

#define LOAD_B(RA, RB) \
    RA = *(const float4*)gb; RB = *(const float4*)(gb + 4); gb += 32;

#define CVT_WRITE_B(SB, RA, RB) { \
    bf16x8 t; \
    t[0] = (__bf16)RA.x; t[1] = (__bf16)RA.y; t[2] = (__bf16)RA.z; t[3] = (__bf16)RA.w; \
    t[4] = (__bf16)RB.x; t[5] = (__bf16)RB.y; t[6] = (__bf16)RB.z; t[7] = (__bf16)RB.w; \
    *(bf16x8*)(Bl[SB] + bwofs) = t; }

#define GEMM_COMPUTE(CB) { \
    bf16x8 af[4], bfr[2]; \
    for (int i = 0; i < 4; i++) \
        af[i] = ldfrag(Al[CB] + (wm + i * 16 + l15) * 32 + quad * 8); \
    for (int j2 = 0; j2 < 2; j2++) \
        bfr[j2] = ldfrag(Bl[CB] + (wn + j2 * 16 + l15) * 32 + quad * 8); \
    for (int i = 0; i < 4; i++) \
        for (int j2 = 0; j2 < 2; j2++) \
            acc[i][j2] = __builtin_amdgcn_mfma_f32_16x16x32_bf16(af[i], bfr[j2], acc[i][j2], 0, 0, 0); }

// iteration t: compute buf C=t&3; stage A of tile t+2 -> buf (t+2)&3; load B
// of tile t+2 -> slot t&1; write B of tile t+1 (slot (t+1)&1) -> buf (t+1)&3.
// vmcnt(4) = only this iteration's 4 ops outstanding -> tile t+1's A+B landed.
// ONE barrier: buffer (t+2)&3's last readers finished before barrier t-1.
#define GITER1(C, S2, W, LA, LB, WA, WB) \
    STAGE_A(S2) \
    LOAD_B(LA, LB) \
    asm volatile("s_waitcnt vmcnt(4)" ::: "memory"); \
    CVT_WRITE_B(W, WA, WB) \
    asm volatile("s_waitcnt lgkmcnt(0)" ::: "memory"); \
    __builtin_amdgcn_s_barrier(); \
    GEMM_COMPUTE(C)

    // prologue: tiles 0,1 in flight; write tile0's B
    STAGE_A(0) LOAD_B(e0a, e0b)
    STAGE_A(1) LOAD_B(e1a, e1b)
    asm volatile("s_waitcnt vmcnt(4)" ::: "memory");   // tile0 A+B landed
    CVT_WRITE_B(0, e0a, e0b)

    // main: t = 0..27 (7 x unroll-4), then t = 28, 29
    for (int kt = 0; kt < 7; kt++) {
        GITER1(0, 2, 1, e0a, e0b, e1a, e1b)
        GITER1(1, 3, 2, e1a, e1b, e0a, e0b)
        GITER1(2, 0, 3, e0a, e0b, e1a, e1b)
        GITER1(3, 1, 0, e1a, e1b, e0a, e0b)
    }
    GITER1(0, 2, 1, e0a, e0b, e1a, e1b)   // t=28: stage t30, write t29, compute t28
    GITER1(1, 3, 2, e1a, e1b, e0a, e0b)   // t=29: stage t31, write t30, compute t29
    // tail: tiles 30 (buf2, already written), 31 (buf3)
    asm volatile("s_waitcnt vmcnt(0)" ::: "memory");
    CVT_WRITE_B(3, e1a, e1b)
    asm volatile("s_waitcnt lgkmcnt(0)" ::: "memory");
    __builtin_amdgcn_s_barrier();
    GEMM_COMPUTE(2)
    GEMM_COMPUTE(3)

#undef STAGE_A
#undef LOAD_B
#undef CVT_WRITE_B
#undef GEMM_COMPUTE
#undef GITER1

    for (int i = 0; i < 4; i++) {
        for (int j2 = 0; j2 < 2; j2++) {
            int nw = nt * 128 + wm + i * 16 + quad * 4;
            int r  = rt * 64 + wn + j2 * 16 + l15;
            if (nt < 8) {
                ushort4 o;
                o.x = f2bf(acc[i][j2][0]); o.y = f2bf(acc[i][j2][1]);
                o.z = f2bf(acc[i][j2][2]); o.w = f2bf(acc[i][j2][3]);
                *(ushort4*)(Qp + (size_t)r * 1024 + nw) = o;
            } else if (nt < 10) {
                ushort4 o;
                o.x = f2bf(acc[i][j2][0]); o.y = f2bf(acc[i][j2][1]);
                o.z = f2bf(acc[i][j2][2]); o.w = f2bf(acc[i][j2][3]);
                *(ushort4*)(Kp + (size_t)r * 256 + (nw - 1024)) = o;
            } else {
                for (int rg = 0; rg < 4; rg++) {
                    int h = nw + rg - 1280;
                    if (h < 16)
                        vproj[((size_t)(r >> 11) * 16 + h) * 2048 + (r & 2047)] = acc[i][j2][rg];
                }
            }
        }
    }
}

// ---------------- attention + fence-free fused combine.
// block = (qt, b*4+kv, ks); wave w -> h = kv*4+w. K via swizzled
// global_load_lds; 4 q-chains/wave; mask as MFMA C-init bias; setprio;
// packed f32x2 accumulate. part written with relaxed AGENT-scope (sc1)
// atomic stores; vmcnt(0)+syncthreads then relaxed agent fetch_add; the
// 32nd arriver of (b,qt) reduces part via agent loads -> out. NO fences.
__global__ __launch_bounds__(256) void attn_kernel(
    const unsigned short* __restrict__ Qp, const unsigned short* __restrict__ Kp,
    const float* __restrict__ vproj, const int* __restrict__ mask,
    float2* __restrict__ part, int* __restrict__ cnt, float* __restrict__ out)
{
    __shared__ __align__(16) unsigned short Kl[256 * 64];
    __shared__ __align__(16) float vpml[4 * 256];
    __shared__ __align__(16) float biasl[256];
    __shared__ int lastflag;
    int qt = blockIdx.x;                       // 0..31
    int b = blockIdx.y >> 2, kv = blockIdx.y & 3;
    int ks = blockIdx.z;                       // 0..7
    int tid = threadIdx.x, lane = tid & 63, w = tid >> 6;
    int l15 = lane & 15, quad = lane >> 4;
    int h = kv * 4 + w;
    int k0 = ks * 256;
    int qrow0 = qt * 64;

    // stage K FIRST (fire-and-forget DMA; latency hides under Q loads below).
    {
        int swz = (lane & 7) ^ ((lane >> 3) & 7);          // lane-pure
        const unsigned short* kbase =
            Kp + (size_t)(b * 2048 + k0 + w * 64 + (lane >> 3)) * 256 + kv * 64 + swz * 8;
        unsigned short* ldst = Kl + (w * 64) * 64;
        #pragma unroll
        for (int j = 0; j < 8; j++)
            gl2lds16(kbase + (size_t)(j * 8) * 256, ldst + j * 8 * 64);
    }

    // Q fragments: B-operand layout B[n=q (l15)][k=d (quad*8..)]
    bf16x8 qf[4][2];
    for (int qs = 0; qs < 4; qs++) {
        const unsigned short* qp =
            Qp + (size_t)(b * 2048 + qrow0 + qs * 16 + l15) * 1024 + h * 64 + quad * 8;
        qf[qs][0] = ldfrag(qp);
        qf[qs][1] = ldfrag(qp + 32);
    }

    {   // vproj slice per h (4 h x 256 k)
        int h2 = tid >> 6, kk = (tid & 63) * 4;
        *(float4*)(vpml + h2 * 256 + kk) =
            *(const float4*)(vproj + ((size_t)b * 16 + kv * 4 + h2) * 2048 + k0 + kk);
    }
    if (tid < 64) {
        int4 mm = *(const int4*)(mask + b * 2048 + k0 + tid * 4);
        float4 bb;
        bb.x = mm.x ? 0.f : -30000.f;
        bb.y = mm.y ? 0.f : -30000.f;
        bb.z = mm.z ? 0.f : -30000.f;
        bb.w = mm.w ? 0.f : -30000.f;
        *(float4*)(biasl + tid * 4) = bb;
    }
    __syncthreads();

    f32x2 nd[4];
    const f32x2 zero2 = {0.f, 0.f};
    for (int qs = 0; qs < 4; qs++) nd[qs] = zero2;

    for (int t8 = 0; t8 < 16; t8++) {
        int r0 = t8 * 16 + l15;
        int rx = r0 & 7;
        bf16x8 a0 = ldfrag(Kl + r0 * 64 + ((quad ^ rx) * 8));
        bf16x8 a1 = ldfrag(Kl + r0 * 64 + (((quad ^ rx) ^ 4) * 8));
        f32x4 vpm4 = *(const f32x4*)(vpml + w * 256 + t8 * 16 + quad * 4);
        f32x4 c4   = *(const f32x4*)(biasl + t8 * 16 + quad * 4);  // mask bias per k-row
        for (int qs = 0; qs < 4; qs++) {
            __builtin_amdgcn_s_setprio(1);
            f32x4 d = __builtin_amdgcn_mfma_f32_16x16x32_bf16(a0, qf[qs][0], c4, 0, 0, 0);
            d = __builtin_amdgcn_mfma_f32_16x16x32_bf16(a1, qf[qs][1], d, 0, 0, 0);
            __builtin_amdgcn_s_setprio(0);
            for (int r = 0; r < 4; r++) {
                float e = __builtin_amdgcn_exp2f(d[r]);   // 0 for masked rows
                f32x2 m = {vpm4[r], 1.0f};
                nd[qs] += m * e;                          // v_pk_fma_f32
            }
        }
    }
    for (int qs = 0; qs < 4; qs++) {
        float n = nd[qs][0], dd = nd[qs][1];
        n += __shfl_xor(n, 16);  n += __shfl_xor(n, 32);
        dd += __shfl_xor(dd, 16); dd += __shfl_xor(dd, 32);
        if (quad == 0) {
            int q = qrow0 + qs * 16 + l15;
            unsigned long long bits =
                __builtin_bit_cast(unsigned long long, make_float2(n, dd));
            __hip_atomic_store(
                (unsigned long long*)(part + (((size_t)(b * 2048 + q) * 16 + h) * 8 + ks)),
                bits, __ATOMIC_RELAXED, __HIP_MEMORY_SCOPE_AGENT);
        }
    }

    // ---- fence-free last-arriver combine (sc1 stores complete -> counter)
    asm volatile("s_waitcnt vmcnt(0)" ::: "memory");   // own sc1 stores at coherence point
    __syncthreads();
    if (tid == 0)
        lastflag = (__hip_atomic_fetch_add(cnt + (b * 32 + qt), 1,
                        __ATOMIC_RELAXED, __HIP_MEMORY_SCOPE_AGENT) == 31);
    __syncthreads();
    if (lastflag) {
        for (int i = 0; i < 16; i++) {
            int q = qrow0 + w * 16 + i;
            const unsigned long long* pb =
                (const unsigned long long*)(part + (size_t)(b * 2048 + q) * 128);
            unsigned long long u0 = __hip_atomic_load(pb + lane,
                __ATOMIC_RELAXED, __HIP_MEMORY_SCOPE_AGENT);
            unsigned long long u1 = __hip_atomic_load(pb + 64 + lane,
                __ATOMIC_RELAXED, __HIP_MEMORY_SCOPE_AGENT);
            float2 p0 = __builtin_bit_cast(float2, u0);
            float2 p1 = __builtin_bit_cast(float2, u1);
            for (int m = 1; m <= 4; m <<= 1) {
                p0.x += __shfl_xor(p0.x, m); p0.y += __shfl_xor(p0.y, m);
                p1.x += __shfl_xor(p1.x, m); p1.y += __shfl_xor(p1.y, m);
            }
            float v = p0.x / p0.y + p1.x / p1.y;
            for (int m = 8; m <= 32; m <<= 1) v += __shfl_xor(v, m);
            if (lane == 0) out[b * 2048 + q] = v;
        }
    }
}

extern "C" void kernel_launch(void* const* d_in, const int* in_sizes, int n_in,
                              void* d_out, int out_size, void* d_ws, size_t ws_size,
                              hipStream_t stream)
{
    const float* hs  = (const float*)d_in[0];
    const int* mask  = (const int*)d_in[1];
    const float* wq  = (const float*)d_in[2];
    const float* wk  = (const float*)d_in[3];
    const float* wv  = (const float*)d_in[4];
    const float* wo  = (const float*)d_in[5];

    char* ws = (char*)d_ws;
    unsigned short* wT = (unsigned short*)ws;                  // 2,883,584 B
    unsigned short* Qp = (unsigned short*)(ws + 2883584);      // 8,388,608 B
    unsigned short* Kp = (unsigned short*)(ws + 11272192);     // 2,097,152 B
    float* vproj       = (float*)(ws + 13369344);              //   262,144 B
    float2* part       = (float2*)(ws + 13631488);             // 4,194,304 B
    int* cnt           = (int*)(ws + 17825792);                //       256 B

    prep_kernel<<<832, 256, 0, stream>>>(wq, wk, wv, wo, wT, cnt);
    gemm_kernel<<<dim3(11, 64), 256, 0, stream>>>(hs, wT, Qp, Kp, vproj);
    attn_kernel<<<dim3(32, 8, 8), 256, 0, stream>>>(Qp, Kp, vproj, mask, part, cnt, (float*)d_out);
}

// Round 13
// 134.183 us; speedup vs baseline: 1.0756x; 1.0756x over previous
//
#include <hip/hip_runtime.h>
#include <stdint.h>

// CoEncoderDynamicAttention: B=2,S=2048,H=1024,NH=16,NKV=4,HD=64, out=(B,S,1)
// out[b,q] = sum_h (sum_k e_{hqk} * vproj[b,h,k]) / (sum_k e_{hqk})
// vproj = hs @ (wv folded with wo); Q' = hs@wq*(log2e/8); weight = exp2(Q'.K);
// mask folded as MFMA accumulator-init bias (0/-30000) -> exp2 gives exact 0.
// R1 gemm dbuf; R2 attn 2048-block structure + setprio; R3 XCD remap + packed
// f32x2 accumulate; R4 attn K via swizzled global_load_lds; R5 gemm 64-r tiles
// + K-DMA-first; R6a hs_bf eliminated; R8 counted-vmcnt; R9 reg-staged bf16 B.
// R13: REVERT R12a (fused combine: agent-scope sc1 traffic + serial L3-latency
//      last-arriver tail cost ~8us vs the 3us combine kernel -- second
//      confirmation that cross-block combine via coherent memory loses on
//      non-coherent-L2 XCDs). KEEP R12b (gemm 4-buf, ONE barrier/iter).

typedef __bf16 bf16x8 __attribute__((ext_vector_type(8)));
typedef float f32x4 __attribute__((ext_vector_type(4)));
typedef float f32x2 __attribute__((ext_vector_type(2)));

__device__ inline unsigned short f2bf(float f) {
    unsigned int u = __builtin_bit_cast(unsigned int, f);
    u += 0x7fff + ((u >> 16) & 1);   // RNE
    return (unsigned short)(u >> 16);
}
__device__ inline bf16x8 ldfrag(const unsigned short* p) {
    uint4 v = *(const uint4*)p;
    return __builtin_bit_cast(bf16x8, v);
}
__device__ inline void gl2lds16(const void* g, void* l) {
    // 64 lanes x 16B: per-lane global addr, LDS dst = wave-uniform base + lane*16
    __builtin_amdgcn_global_load_lds(
        (const __attribute__((address_space(1))) void*)g,
        (__attribute__((address_space(3))) void*)l, 16, 0, 0);
}

#define SCALE_Q 0.18033688011112042f   // log2(e)/8

// ---------------- prep: wT = [wq^T*s | wk^T | wvo^T | zeros] (1408x1024 bf16)
__global__ __launch_bounds__(256) void prep_kernel(
    const float* __restrict__ wq, const float* __restrict__ wk,
    const float* __restrict__ wv, const float* __restrict__ wo,
    unsigned short* __restrict__ wT)
{
    int bid = blockIdx.x, tid = threadIdx.x;
    if (bid < 320) {
        __shared__ float tile[64 * 65];
        int t = bid;
        int ntile = t / 16, ctile = t % 16;
        int nb = ntile * 64, cb = ctile * 64;
        int tx = tid & 63, ty = tid >> 6;
        for (int i = 0; i < 16; i++) {
            int cl = i * 4 + ty;
            int n = nb + tx;
            float v = (n < 1024) ? wq[(cb + cl) * 1024 + n] * SCALE_Q
                                 : wk[(cb + cl) * 256 + (n - 1024)];
            tile[cl * 65 + tx] = v;
        }
        __syncthreads();
        for (int i = 0; i < 16; i++) {
            int nl = i * 4 + ty;
            wT[(nb + nl) * 1024 + cb + tx] = f2bf(tile[tx * 65 + nl]);
        }
    } else {
        int u = (bid - 320) * 256 + tid;
        int n2 = u >> 10, c = u & 1023;
        if (n2 < 16) {
            int h = n2, kv = h >> 2;
            const float* wvr = wv + c * 256 + kv * 64;
            const float* wor = wo + h * 64;
            float s = 0.f;
            #pragma unroll 8
            for (int d = 0; d < 64; d++) s += wvr[d] * wor[d];
            wT[(1280 + n2) * 1024 + c] = f2bf(s);
        } else {
            wT[(1280 + n2) * 1024 + c] = 0;
        }
    }
}

// ---------------- gemm (4-buf, ONE barrier/iter, counted vmcnt, reg-staged
// bf16 B, XCD remap, 128n x 64r): D[n][r] = sum_c wT[n][c]*hs[r][c].
// n-tiles: 0..7 Q', 8..9 K, 10 vproj f32.
__global__ __launch_bounds__(256) void gemm_kernel(
    const float* __restrict__ hs, const unsigned short* __restrict__ wT,
    unsigned short* __restrict__ Qp, unsigned short* __restrict__ Kp,
    float* __restrict__ vproj)
{
    __shared__ __align__(16) unsigned short Al[4][128 * 32];  // 32 KB
    __shared__ __align__(16) unsigned short Bl[4][64 * 32];   // 16 KB
    // XCD remap: XCD x gets rt-groups x*8..x*8+7 (88 = 8rt x 11nt).
    int p = blockIdx.x + 11 * blockIdx.y;   // 0..703
    int xcd = p & 7;
    int j = p >> 3;                          // 0..87
    int rt = (xcd << 3) + j / 11;            // 0..63
    int nt = j % 11;
    int tid = threadIdx.x;
    int lane = tid & 63, w = tid >> 6;
    int l15 = lane & 15, quad = lane >> 4;
    int wm = (w >> 1) * 64, wn = (w & 1) * 32;

    f32x4 acc[4][2];
    const f32x4 zero = {0.f, 0.f, 0.f, 0.f};
    for (int i = 0; i < 4; i++) for (int j2 = 0; j2 < 2; j2++) acc[i][j2] = zero;

    int arow = nt * 128, rrow = rt * 64;
    int srowA = w * 32 + (lane >> 2);
    int scolA = (lane & 3) * 8;
    const unsigned short* ga = wT + (size_t)(arow + srowA) * 1024 + scolA;
    int lofsA = (w * 32) * 32;
    int rWl = w * 16 + (lane >> 2);          // 0..63 within tile
    const float* gb = hs + (size_t)(rrow + rWl) * 1024 + (lane & 3) * 8;
    int bwofs = rWl * 32 + (lane & 3) * 8;

    float4 e0a, e0b, e1a, e1b;               // 2 B-reg slots (tile parity)

#define STAGE_A(SB) \
    gl2lds16(ga,             Al[SB] + lofsA); \
    gl2lds16(ga + 16 * 1024, Al[SB] + lofsA + 16 * 32); \
    ga += 32;

#define LOAD_B(RA, RB) \
    RA = *(const float4*)gb; RB = *(const float4*)(gb + 4); gb += 32;

#define CVT_WRITE_B(SB, RA, RB) { \
    bf16x8 t; \
    t[0] = (__bf16)RA.x; t[1] = (__bf16)RA.y; t[2] = (__bf16)RA.z; t[3] = (__bf16)RA.w; \
    t[4] = (__bf16)RB.x; t[5] = (__bf16)RB.y; t[6] = (__bf16)RB.z; t[7] = (__bf16)RB.w; \
    *(bf16x8*)(Bl[SB] + bwofs) = t; }

#define GEMM_COMPUTE(CB) { \
    bf16x8 af[4], bfr[2]; \
    for (int i = 0; i < 4; i++) \
        af[i] = ldfrag(Al[CB] + (wm + i * 16 + l15) * 32 + quad * 8); \
    for (int j2 = 0; j2 < 2; j2++) \
        bfr[j2] = ldfrag(Bl[CB] + (wn + j2 * 16 + l15) * 32 + quad * 8); \
    for (int i = 0; i < 4; i++) \
        for (int j2 = 0; j2 < 2; j2++) \
            acc[i][j2] = __builtin_amdgcn_mfma_f32_16x16x32_bf16(af[i], bfr[j2], acc[i][j2], 0, 0, 0); }

// iteration t: compute buf C=t&3; stage A of tile t+2 -> buf (t+2)&3; load B
// of tile t+2 -> slot t&1; write B of tile t+1 (slot (t+1)&1) -> buf (t+1)&3.
// vmcnt(4) = only this iteration's 4 ops outstanding -> tile t+1's A+B landed.
// ONE barrier: buffer (t+2)&3's last readers finished before barrier t-1.
#define GITER1(C, S2, W, LA, LB, WA, WB) \
    STAGE_A(S2) \
    LOAD_B(LA, LB) \
    asm volatile("s_waitcnt vmcnt(4)" ::: "memory"); \
    CVT_WRITE_B(W, WA, WB) \
    asm volatile("s_waitcnt lgkmcnt(0)" ::: "memory"); \
    __builtin_amdgcn_s_barrier(); \
    GEMM_COMPUTE(C)

    // prologue: tiles 0,1 in flight; write tile0's B
    STAGE_A(0) LOAD_B(e0a, e0b)
    STAGE_A(1) LOAD_B(e1a, e1b)
    asm volatile("s_waitcnt vmcnt(4)" ::: "memory");   // tile0 A+B landed
    CVT_WRITE_B(0, e0a, e0b)

    // main: t = 0..27 (7 x unroll-4), then t = 28, 29
    for (int kt = 0; kt < 7; kt++) {
        GITER1(0, 2, 1, e0a, e0b, e1a, e1b)
        GITER1(1, 3, 2, e1a, e1b, e0a, e0b)
        GITER1(2, 0, 3, e0a, e0b, e1a, e1b)
        GITER1(3, 1, 0, e1a, e1b, e0a, e0b)
    }
    GITER1(0, 2, 1, e0a, e0b, e1a, e1b)   // t=28: stage t30, write t29, compute t28
    GITER1(1, 3, 2, e1a, e1b, e0a, e0b)   // t=29: stage t31, write t30, compute t29
    // tail: tiles 30 (buf2, already written), 31 (buf3)
    asm volatile("s_waitcnt vmcnt(0)" ::: "memory");
    CVT_WRITE_B(3, e1a, e1b)
    asm volatile("s_waitcnt lgkmcnt(0)" ::: "memory");
    __builtin_amdgcn_s_barrier();
    GEMM_COMPUTE(2)
    GEMM_COMPUTE(3)

#undef STAGE_A
#undef LOAD_B
#undef CVT_WRITE_B
#undef GEMM_COMPUTE
#undef GITER1

    for (int i = 0; i < 4; i++) {
        for (int j2 = 0; j2 < 2; j2++) {
            int nw = nt * 128 + wm + i * 16 + quad * 4;
            int r  = rt * 64 + wn + j2 * 16 + l15;
            if (nt < 8) {
                ushort4 o;
                o.x = f2bf(acc[i][j2][0]); o.y = f2bf(acc[i][j2][1]);
                o.z = f2bf(acc[i][j2][2]); o.w = f2bf(acc[i][j2][3]);
                *(ushort4*)(Qp + (size_t)r * 1024 + nw) = o;
            } else if (nt < 10) {
                ushort4 o;
                o.x = f2bf(acc[i][j2][0]); o.y = f2bf(acc[i][j2][1]);
                o.z = f2bf(acc[i][j2][2]); o.w = f2bf(acc[i][j2][3]);
                *(ushort4*)(Kp + (size_t)r * 256 + (nw - 1024)) = o;
            } else {
                for (int rg = 0; rg < 4; rg++) {
                    int h = nw + rg - 1280;
                    if (h < 16)
                        vproj[((size_t)(r >> 11) * 16 + h) * 2048 + (r & 2047)] = acc[i][j2][rg];
                }
            }
        }
    }
}

// ---------------- attention: block = (qt, b*4+kv, ks); wave w -> h = kv*4+w.
// K tile via swizzled global_load_lds (conflict-free, DMA-first);
// 4 independent q-chains/wave; mask as MFMA C-init bias; setprio (T5);
// packed f32x2 accumulate. LDS 37KB, 88 VGPR -> 4 blocks/CU.
__global__ __launch_bounds__(256) void attn_kernel(
    const unsigned short* __restrict__ Qp, const unsigned short* __restrict__ Kp,
    const float* __restrict__ vproj, const int* __restrict__ mask,
    float2* __restrict__ part)
{
    __shared__ __align__(16) unsigned short Kl[256 * 64];
    __shared__ __align__(16) float vpml[4 * 256];
    __shared__ __align__(16) float biasl[256];
    int qt = blockIdx.x;                       // 0..31
    int b = blockIdx.y >> 2, kv = blockIdx.y & 3;
    int ks = blockIdx.z;                       // 0..7
    int tid = threadIdx.x, lane = tid & 63, w = tid >> 6;
    int l15 = lane & 15, quad = lane >> 4;
    int h = kv * 4 + w;
    int k0 = ks * 256;
    int qrow0 = qt * 64;

    // stage K FIRST (fire-and-forget DMA; latency hides under Q loads below).
    {
        int swz = (lane & 7) ^ ((lane >> 3) & 7);          // lane-pure
        const unsigned short* kbase =
            Kp + (size_t)(b * 2048 + k0 + w * 64 + (lane >> 3)) * 256 + kv * 64 + swz * 8;
        unsigned short* ldst = Kl + (w * 64) * 64;
        #pragma unroll
        for (int j = 0; j < 8; j++)
            gl2lds16(kbase + (size_t)(j * 8) * 256, ldst + j * 8 * 64);
    }

    // Q fragments: B-operand layout B[n=q (l15)][k=d (quad*8..)]
    bf16x8 qf[4][2];
    for (int qs = 0; qs < 4; qs++) {
        const unsigned short* qp =
            Qp + (size_t)(b * 2048 + qrow0 + qs * 16 + l15) * 1024 + h * 64 + quad * 8;
        qf[qs][0] = ldfrag(qp);
        qf[qs][1] = ldfrag(qp + 32);
    }

    {   // vproj slice per h (4 h x 256 k)
        int h2 = tid >> 6, kk = (tid & 63) * 4;
        *(float4*)(vpml + h2 * 256 + kk) =
            *(const float4*)(vproj + ((size_t)b * 16 + kv * 4 + h2) * 2048 + k0 + kk);
    }
    if (tid < 64) {
        int4 mm = *(const int4*)(mask + b * 2048 + k0 + tid * 4);
        float4 bb;
        bb.x = mm.x ? 0.f : -30000.f;
        bb.y = mm.y ? 0.f : -30000.f;
        bb.z = mm.z ? 0.f : -30000.f;
        bb.w = mm.w ? 0.f : -30000.f;
        *(float4*)(biasl + tid * 4) = bb;
    }
    __syncthreads();

    f32x2 nd[4];
    const f32x2 zero2 = {0.f, 0.f};
    for (int qs = 0; qs < 4; qs++) nd[qs] = zero2;

    for (int t8 = 0; t8 < 16; t8++) {
        int r0 = t8 * 16 + l15;
        int rx = r0 & 7;
        bf16x8 a0 = ldfrag(Kl + r0 * 64 + ((quad ^ rx) * 8));
        bf16x8 a1 = ldfrag(Kl + r0 * 64 + (((quad ^ rx) ^ 4) * 8));
        f32x4 vpm4 = *(const f32x4*)(vpml + w * 256 + t8 * 16 + quad * 4);
        f32x4 c4   = *(const f32x4*)(biasl + t8 * 16 + quad * 4);  // mask bias per k-row
        for (int qs = 0; qs < 4; qs++) {
            __builtin_amdgcn_s_setprio(1);
            f32x4 d = __builtin_amdgcn_mfma_f32_16x16x32_bf16(a0, qf[qs][0], c4, 0, 0, 0);
            d = __builtin_amdgcn_mfma_f32_16x16x32_bf16(a1, qf[qs][1], d, 0, 0, 0);
            __builtin_amdgcn_s_setprio(0);
            for (int r = 0; r < 4; r++) {
                float e = __builtin_amdgcn_exp2f(d[r]);   // 0 for masked rows
                f32x2 m = {vpm4[r], 1.0f};
                nd[qs] += m * e;                          // v_pk_fma_f32
            }
        }
    }
    for (int qs = 0; qs < 4; qs++) {
        float n = nd[qs][0], dd = nd[qs][1];
        n += __shfl_xor(n, 16);  n += __shfl_xor(n, 32);
        dd += __shfl_xor(dd, 16); dd += __shfl_xor(dd, 32);
        if (quad == 0) {
            int q = qrow0 + qs * 16 + l15;
            part[((size_t)(b * 2048 + q) * 16 + h) * 8 + ks] = make_float2(n, dd);
        }
    }
}

// ---------------- combine: out[b,q] = sum_h (sum_ks num)/(sum_ks den)
__global__ __launch_bounds__(256) void combine_kernel(
    const float2* __restrict__ part, float* __restrict__ out)
{
    int wid = (blockIdx.x * 256 + threadIdx.x) >> 6;  // (b,q)
    int lane = threadIdx.x & 63;
    const float2* base = part + (size_t)wid * 128;    // 16 h x 8 ks
    float2 p0 = base[lane];
    float2 p1 = base[64 + lane];
    for (int m = 1; m <= 4; m <<= 1) {
        p0.x += __shfl_xor(p0.x, m); p0.y += __shfl_xor(p0.y, m);
        p1.x += __shfl_xor(p1.x, m); p1.y += __shfl_xor(p1.y, m);
    }
    float v = p0.x / p0.y + p1.x / p1.y;
    for (int m = 8; m <= 32; m <<= 1) v += __shfl_xor(v, m);  // 8 distinct h-groups, once each
    if (lane == 0) out[wid] = v;
}

extern "C" void kernel_launch(void* const* d_in, const int* in_sizes, int n_in,
                              void* d_out, int out_size, void* d_ws, size_t ws_size,
                              hipStream_t stream)
{
    const float* hs  = (const float*)d_in[0];
    const int* mask  = (const int*)d_in[1];
    const float* wq  = (const float*)d_in[2];
    const float* wk  = (const float*)d_in[3];
    const float* wv  = (const float*)d_in[4];
    const float* wo  = (const float*)d_in[5];

    char* ws = (char*)d_ws;
    unsigned short* wT = (unsigned short*)ws;                  // 2,883,584 B
    unsigned short* Qp = (unsigned short*)(ws + 2883584);      // 8,388,608 B
    unsigned short* Kp = (unsigned short*)(ws + 11272192);     // 2,097,152 B
    float* vproj       = (float*)(ws + 13369344);              //   262,144 B
    float2* part       = (float2*)(ws + 13631488);             // 4,194,304 B

    prep_kernel<<<832, 256, 0, stream>>>(wq, wk, wv, wo, wT);
    gemm_kernel<<<dim3(11, 64), 256, 0, stream>>>(hs, wT, Qp, Kp, vproj);
    attn_kernel<<<dim3(32, 8, 8), 256, 0, stream>>>(Qp, Kp, vproj, mask, part);
    combine_kernel<<<1024, 256, 0, stream>>>(part, (float*)d_out);
}